// Round 4
// baseline (3243.271 us; speedup 1.0000x reference)
//
#include <hip/hip_runtime.h>

#define T_   500
#define B_   32
#define IN_  512
#define H_   1024
#define KTOT 1536
#define NWG  256
#define NPD  128    // WGs per direction
#define NR   32     // gate rows per WG
#define WSTR 1544   // LDS row stride in f16 elems (dword-stride 772 === 4 mod 32 -> 2-way max on b128)

typedef _Float16 f16x8 __attribute__((ext_vector_type(8)));
typedef _Float16 f16x4 __attribute__((ext_vector_type(4)));
typedef float    f32x4 __attribute__((ext_vector_type(4)));

#define MFMA __builtin_amdgcn_mfma_f32_16x16x32_f16

// ---------------------------------------------------------------- x -> fp16
__global__ void cvt_x_kernel(const float* __restrict__ x, _Float16* __restrict__ xb, int n8) {
  int i = blockIdx.x * blockDim.x + threadIdx.x;
  if (i >= n8) return;
  const float4* p = (const float4*)x + (size_t)i * 2;
  float4 v0 = p[0], v1 = p[1];
  f16x8 o = { (_Float16)v0.x, (_Float16)v0.y, (_Float16)v0.z, (_Float16)v0.w,
              (_Float16)v1.x, (_Float16)v1.y, (_Float16)v1.z, (_Float16)v1.w };
  *((f16x8*)xb + i) = o;
}

// ---------------------------------------------------------------- persistent LSTM
__global__ __launch_bounds__(256, 1) void lstm_kernel(
    const float* __restrict__ w_ih_f, const float* __restrict__ w_hh_f,
    const float* __restrict__ b_ih_f, const float* __restrict__ b_hh_f,
    const float* __restrict__ w_ih_r, const float* __restrict__ w_hh_r,
    const float* __restrict__ b_ih_r, const float* __restrict__ b_hh_r,
    const _Float16* __restrict__ xb,
    unsigned* __restrict__ flags, float* __restrict__ out)
{
  __shared__ _Float16 Wl[NR * WSTR];        // 98,816 B : [w_ih | w_hh] slice, fp16
  __shared__ float glA[NR][NR + 1];         //  4,224 B : partial gates, K-half 0
  __shared__ float glB[NR][NR + 1];         //  4,224 B : partial gates, K-half 1

  const int wg   = blockIdx.x;
  const int dir  = wg >> 7;
  const int slot = wg & 127;
  const int col0 = slot * 8;
  const int tid  = threadIdx.x;

  const float* w_ih = dir ? w_ih_r : w_ih_f;
  const float* w_hh = dir ? w_hh_r : w_hh_f;
  const float* b_ih = dir ? b_ih_r : b_ih_f;
  const float* b_hh = dir ? b_hh_r : b_hh_f;

  unsigned* fl = flags + dir * NPD;

  // ---- stage combined weight slice into LDS as fp16 ----
  for (int i = tid; i < NR * (KTOT / 4); i += 256) {
    int r  = i / (KTOT / 4);
    int k  = (i - r * (KTOT / 4)) * 4;
    int gr = (r >> 3) * H_ + col0 + (r & 7);
    float4 v = (k < IN_) ? *(const float4*)(w_ih + (size_t)gr * IN_ + k)
                         : *(const float4*)(w_hh + (size_t)gr * H_ + (k - IN_));
    f16x4 h4 = { (_Float16)v.x, (_Float16)v.y, (_Float16)v.z, (_Float16)v.w };
    *(f16x4*)(&Wl[r * WSTR + k]) = h4;
  }

  // ---- per-thread (b, h-col) ownership ----
  const int tb = tid >> 3, thc = tid & 7, tcol = col0 + thc;
  const float bias0 = b_ih[0 * H_ + tcol] + b_hh[0 * H_ + tcol];
  const float bias1 = b_ih[1 * H_ + tcol] + b_hh[1 * H_ + tcol];
  const float bias2 = b_ih[2 * H_ + tcol] + b_hh[2 * H_ + tcol];
  const float bias3 = b_ih[3 * H_ + tcol] + b_hh[3 * H_ + tcol];
  float c = 0.f;

  __syncthreads();   // weights staged

  // ---- wave tiling: wave w = (m-half, K-parity) ; each wave does BOTH n-tiles ----
  const int lane = tid & 63, wv = tid >> 6;
  const int mh = wv & 1, kh = wv >> 1;       // m-half (batch), K-interleave parity
  const int frow = lane & 15, fkb = lane >> 4;
  const int mrow = mh * 16 + frow;           // batch row this lane supplies
  const int kbase = 32 * kh + 8 * fkb;       // k elem offset for slice j: 64j + kbase
  const _Float16* bW0 = &Wl[frow * WSTR + kbase];          // n-tile 0 (rows 0..15)
  const _Float16* bW1 = &Wl[(16 + frow) * WSTR + kbase];   // n-tile 1 (rows 16..31)

  for (int s = 0; s < T_; ++s) {
    const int tx = dir ? (T_ - 1 - s) : s;

    // ===== phase 1: x-part (k = 0..511 interleaved) — cached fp16 loads =====
    const _Float16* aX = xb + ((size_t)tx * B_ + mrow) * IN_ + kbase;
    f32x4 p0[2] = {{0,0,0,0},{0,0,0,0}}, p1[2] = {{0,0,0,0},{0,0,0,0}};
#pragma unroll
    for (int j = 0; j < 8; ++j) {
      f16x8 xf = *(const f16x8*)(aX + 64 * j);
      p0[j & 1] = MFMA(xf, *(const f16x8*)(bW0 + 64 * j), p0[j & 1], 0, 0, 0);
      p1[j & 1] = MFMA(xf, *(const f16x8*)(bW1 + 64 * j), p1[j & 1], 0, 0, 0);
    }

    if (s > 0) {
      // ===== phase 2: wait for h(s) (out row txp) published by all WGs =====
      if (wv == 0) {
        const unsigned tgt = (unsigned)s;
        int guard = 0;
        for (;;) {
          unsigned f0 = __hip_atomic_load(fl + lane,      __ATOMIC_RELAXED, __HIP_MEMORY_SCOPE_AGENT);
          unsigned f1 = __hip_atomic_load(fl + 64 + lane, __ATOMIC_RELAXED, __HIP_MEMORY_SCOPE_AGENT);
          if (__all(f0 >= tgt && f1 >= tgt)) break;
          __builtin_amdgcn_s_sleep(1);
          if (++guard > (1 << 22)) break;   // failsafe: fail loud, not hang
        }
      }
      __syncthreads();
      asm volatile("" ::: "memory");        // compiler fence: no load hoisting above the wait

      // ===== phase 3: h-part — CACHED fp32 reads from out (write-once => never stale) =====
      const int txp = dir ? (T_ - s) : (s - 1);
      const float* aH = out + ((size_t)txp * B_ + mrow) * (2 * H_) + dir * H_ + kbase;
#pragma unroll
      for (int j = 0; j < 16; ++j) {
        f32x4 lo = *(const f32x4*)(aH + 64 * j);
        f32x4 hi = *(const f32x4*)(aH + 64 * j + 4);
        f16x8 hf = { (_Float16)lo[0], (_Float16)lo[1], (_Float16)lo[2], (_Float16)lo[3],
                     (_Float16)hi[0], (_Float16)hi[1], (_Float16)hi[2], (_Float16)hi[3] };
        p0[j & 1] = MFMA(hf, *(const f16x8*)(bW0 + 512 + 64 * j), p0[j & 1], 0, 0, 0);
        p1[j & 1] = MFMA(hf, *(const f16x8*)(bW1 + 512 + 64 * j), p1[j & 1], 0, 0, 0);
      }
    }

    f32x4 an0 = p0[0] + p0[1];
    f32x4 an1 = p1[0] + p1[1];

    // D layout (m89): col = lane&15 (n), row = (lane>>4)*4 + reg (m)
    float* gld = kh ? &glB[0][0] : &glA[0][0];
    const int grow = mh * 16 + fkb * 4;
#pragma unroll
    for (int i = 0; i < 4; ++i) {
      gld[(grow + i) * (NR + 1) + frow]      = an0[i];
      gld[(grow + i) * (NR + 1) + 16 + frow] = an1[i];
    }
    __syncthreads();

    // ===== phase 4: gates / state update =====
    float xi  = glA[tb][ 0 + thc] + glB[tb][ 0 + thc] + bias0;
    float xf_ = glA[tb][ 8 + thc] + glB[tb][ 8 + thc] + bias1;
    float xg  = glA[tb][16 + thc] + glB[tb][16 + thc] + bias2;
    float xo  = glA[tb][24 + thc] + glB[tb][24 + thc] + bias3;
    float ig = fminf(fmaxf(0.2f * xi  + 0.5f, 0.f), 1.f);
    float fg = fminf(fmaxf(0.2f * xf_ + 0.5f, 0.f), 1.f);
    float cg = fminf(fmaxf(xg, -1.f), 1.f);
    float og = fminf(fmaxf(0.2f * xo  + 0.5f, 0.f), 1.f);
    c = fg * c + ig * cg;
    float hv = og * fminf(fmaxf(c, -1.f), 1.f);

    { // publish: write-through to MALL; this IS both the output write and the h-exchange
      float* op = out + ((size_t)tx * B_ + tb) * (2 * H_) + dir * H_ + tcol;
      asm volatile("global_store_dword %0, %1, off sc0 sc1" :: "v"(op), "v"(hv) : "memory");
    }
    if (s == T_ - 1) {
      const size_t HY = (size_t)T_ * B_ * 2 * H_;
      out[HY + ((size_t)dir * B_ + tb) * H_ + tcol] = hv;                           // hy
      out[HY + (size_t)2 * B_ * H_ + ((size_t)dir * B_ + tb) * H_ + tcol] = c;      // cy
    }

    // ===== phase 5: release + arrive =====
    asm volatile("s_waitcnt vmcnt(0)" ::: "memory");   // own out-store ack'd at MALL
    __syncthreads();                                   // all 256 threads ack'd
    if (tid == 0)
      __hip_atomic_store(fl + slot, (unsigned)(s + 1), __ATOMIC_RELAXED, __HIP_MEMORY_SCOPE_AGENT);
    // next iteration's x-part overlaps flag propagation
  }
}

// ---------------------------------------------------------------- launcher
extern "C" void kernel_launch(void* const* d_in, const int* in_sizes, int n_in,
                              void* d_out, int out_size, void* d_ws, size_t ws_size,
                              hipStream_t stream) {
  const float* x      = (const float*)d_in[0];
  const float* w_ih_f = (const float*)d_in[1];
  const float* w_hh_f = (const float*)d_in[2];
  const float* b_ih_f = (const float*)d_in[3];
  const float* b_hh_f = (const float*)d_in[4];
  const float* w_ih_r = (const float*)d_in[5];
  const float* w_hh_r = (const float*)d_in[6];
  const float* b_ih_r = (const float*)d_in[7];
  const float* b_hh_r = (const float*)d_in[8];
  float* out = (float*)d_out;

  char* ws = (char*)d_ws;
  _Float16* xb    = (_Float16*)ws;             // 16,384,000 B  (T*B*IN f16)
  unsigned* flags = (unsigned*)(ws + 16384000);//      1,024 B  (2 dir * 128 arrival flags)

  hipMemsetAsync(flags, 0, 1024, stream);
  cvt_x_kernel<<<4000, 256, 0, stream>>>(x, xb, 1024000);
  lstm_kernel<<<NWG, 256, 0, stream>>>(w_ih_f, w_hh_f, b_ih_f, b_hh_f,
                                       w_ih_r, w_hh_r, b_ih_r, b_hh_r,
                                       xb, flags, out);
}

// Round 5
// 2313.604 us; speedup vs baseline: 1.4018x; 1.4018x over previous
//
#include <hip/hip_runtime.h>

#define T_   500
#define B_   32
#define IN_  512
#define H_   1024
#define NWG  128    // total WGs (64 per direction)
#define NPD  64     // WGs per direction
#define THR  512    // threads per WG (8 waves)

typedef _Float16 f16x8 __attribute__((ext_vector_type(8)));
typedef float    f32x4 __attribute__((ext_vector_type(4)));

#define MFMA __builtin_amdgcn_mfma_f32_16x16x32_f16

// counted vmem wait + scheduling fence (rule #18: MFMA hoists past bare asm waitcnt)
#define WAITV(N) do { asm volatile("s_waitcnt vmcnt(" #N ")" ::: "memory"); \
                      __builtin_amdgcn_sched_barrier(0); } while (0)

// coherent (MALL) 16B load of h fragment: bypasses L1/L2 -> no acquire-invalidate needed
#define HLOAD(r, ks) \
  asm volatile("global_load_dwordx4 %0, %1, off offset:%2 sc0 sc1" \
               : "=v"(hf##r) : "v"(aH), "i"(64 * (ks)) : "memory")

// one h k-step: A-frag hf##r against 4 n-tile B-frags from swizzled LDS
#define HSTEP(r, ks) do { \
  const int t_ = (kq512 + (ks) * 64 + fkb16) ^ sw; \
  acc0 = MFMA(hf##r, *(const f16x8*)(WhB0 + t_), acc0, 0, 0, 0); \
  acc1 = MFMA(hf##r, *(const f16x8*)(WhB1 + t_), acc1, 0, 0, 0); \
  acc2 = MFMA(hf##r, *(const f16x8*)(WhB2 + t_), acc2, 0, 0, 0); \
  acc3 = MFMA(hf##r, *(const f16x8*)(WhB3 + t_), acc3, 0, 0, 0); } while (0)

__device__ __forceinline__ f16x8 cvt8(float4 lo, float4 hi) {
  return (f16x8){ (_Float16)lo.x, (_Float16)lo.y, (_Float16)lo.z, (_Float16)lo.w,
                  (_Float16)hi.x, (_Float16)hi.y, (_Float16)hi.z, (_Float16)hi.w };
}

// ---------------------------------------------------------------- x -> fp16
__global__ void cvt_x_kernel(const float* __restrict__ x, _Float16* __restrict__ xb, int n8) {
  int i = blockIdx.x * blockDim.x + threadIdx.x;
  if (i >= n8) return;
  const float4* p = (const float4*)x + (size_t)i * 2;
  *((f16x8*)xb + i) = cvt8(p[0], p[1]);
}

// ---------------------------------------------------------------- persistent LSTM
__global__ __launch_bounds__(THR, 1) void lstm_kernel(
    const float* __restrict__ w_ih_f, const float* __restrict__ w_hh_f,
    const float* __restrict__ b_ih_f, const float* __restrict__ b_hh_f,
    const float* __restrict__ w_ih_r, const float* __restrict__ w_hh_r,
    const float* __restrict__ b_ih_r, const float* __restrict__ b_hh_r,
    const _Float16* __restrict__ xb, _Float16* __restrict__ hb,
    unsigned* __restrict__ flags, float* __restrict__ out)
{
  __shared__ _Float16 Wh[64 * 1024];   // 131,072 B : h-weights, XOR-swizzled rows
  __shared__ float    pg[4][32][64];   //  32,768 B : K-quarter partial gates
  // total 163,840 B = 160 KiB (device max)

  const int wg   = blockIdx.x;
  const int dir  = wg >> 6;
  const int slot = wg & 63;
  const int col0 = slot * 16;          // first owned h-column (16 per WG)
  const int tid  = threadIdx.x;

  const float* w_ih = dir ? w_ih_r : w_ih_f;
  const float* w_hh = dir ? w_hh_r : w_hh_f;
  const float* b_ih = dir ? b_ih_r : b_ih_f;
  const float* b_hh = dir ? b_hh_r : b_hh_f;

  unsigned* fl = flags + dir * NPD;

  // ---- stage h-weights into LDS, fp16, row r -> gate row (r>>4)*H + col0 + (r&15),
  //      byte offset r*2048 + ((k*2) ^ ((r&7)<<4))  (swizzled, 16B-aligned)
  for (int i = tid; i < 64 * 128; i += THR) {
    const int r  = i >> 7;
    const int k  = (i & 127) * 8;
    const int gr = (r >> 4) * H_ + col0 + (r & 15);
    const float4* p = (const float4*)(w_hh + (size_t)gr * H_ + k);
    const int byte = r * 2048 + ((k * 2) ^ ((r & 7) << 4));
    *(f16x8*)((char*)Wh + byte) = cvt8(p[0], p[1]);
  }

  // ---- wave tiling: wave = (m-half, K-quarter); each wave does all 4 n-tiles ----
  const int lane = tid & 63, wv = tid >> 6;
  const int mh = wv & 1, kq = wv >> 1;       // m-half (batch), K-quarter
  const int frow = lane & 15, fkb = lane >> 4;
  const int mrow = mh * 16 + frow;           // batch row this lane supplies
  const int sw    = (frow & 7) << 4;         // LDS row swizzle
  const int kq512 = kq * 512;                // h k-quarter byte base
  const int fkb16 = fkb * 16;
  const char* WhB0 = (const char*)Wh + (size_t)( 0 + frow) * 2048;
  const char* WhB1 = (const char*)Wh + (size_t)(16 + frow) * 2048;
  const char* WhB2 = (const char*)Wh + (size_t)(32 + frow) * 2048;
  const char* WhB3 = (const char*)Wh + (size_t)(48 + frow) * 2048;

  // ---- x-weights: resident in registers (16 B-frags = 32 VGPRs), fp32 -> fp16 once
  f16x8 xw0[4], xw1[4], xw2[4], xw3[4];
#pragma unroll
  for (int ks = 0; ks < 4; ++ks) {
    const int k = kq * 128 + ks * 32 + fkb * 8;
    { const float4* p = (const float4*)(w_ih + (size_t)(0 * H_ + col0 + frow) * IN_ + k);
      xw0[ks] = cvt8(p[0], p[1]); }
    { const float4* p = (const float4*)(w_ih + (size_t)(1 * H_ + col0 + frow) * IN_ + k);
      xw1[ks] = cvt8(p[0], p[1]); }
    { const float4* p = (const float4*)(w_ih + (size_t)(2 * H_ + col0 + frow) * IN_ + k);
      xw2[ks] = cvt8(p[0], p[1]); }
    { const float4* p = (const float4*)(w_ih + (size_t)(3 * H_ + col0 + frow) * IN_ + k);
      xw3[ks] = cvt8(p[0], p[1]); }
  }

  // ---- per-thread (b, h-col) ownership for gates/state ----
  const int tb = tid >> 4, thc = tid & 15, tcol = col0 + thc;
  const float b0 = b_ih[0 * H_ + tcol] + b_hh[0 * H_ + tcol];
  const float b1 = b_ih[1 * H_ + tcol] + b_hh[1 * H_ + tcol];
  const float b2 = b_ih[2 * H_ + tcol] + b_hh[2 * H_ + tcol];
  const float b3 = b_ih[3 * H_ + tcol] + b_hh[3 * H_ + tcol];
  float c = 0.f;

  const size_t hbase = (size_t)(dir * 2) * B_ * H_;

  __syncthreads();   // weights staged

  for (int s = 0; s < T_; ++s) {
    const int tx = dir ? (T_ - 1 - s) : s;

    // ===== phase 1: x-part — cached A loads, register B =====
    const _Float16* aX = xb + ((size_t)tx * B_ + mrow) * IN_ + kq * 128 + fkb * 8;
    f32x4 acc0 = {0,0,0,0}, acc1 = {0,0,0,0}, acc2 = {0,0,0,0}, acc3 = {0,0,0,0};
#pragma unroll
    for (int ks = 0; ks < 4; ++ks) {
      f16x8 xa = *(const f16x8*)(aX + ks * 32);
      acc0 = MFMA(xa, xw0[ks], acc0, 0, 0, 0);
      acc1 = MFMA(xa, xw1[ks], acc1, 0, 0, 0);
      acc2 = MFMA(xa, xw2[ks], acc2, 0, 0, 0);
      acc3 = MFMA(xa, xw3[ks], acc3, 0, 0, 0);
    }
    __builtin_amdgcn_sched_barrier(0);   // keep x-part ahead of the wait

    if (s > 0) {
      // ===== phase 2: wait for h(s) published by all 64 WGs of this direction =====
      if (wv == 0) {
        const unsigned tgt = (unsigned)s;
        int guard = 0;
        for (;;) {
          unsigned f = __hip_atomic_load(fl + lane, __ATOMIC_RELAXED, __HIP_MEMORY_SCOPE_AGENT);
          if (__all(f >= tgt)) break;
          __builtin_amdgcn_s_sleep(1);
          if (++guard > (1 << 22)) break;   // failsafe: fail loud, not hang
        }
      }
      __syncthreads();
      asm volatile("" ::: "memory");

      // ===== phase 3: h-part — coherent bypass loads, depth-pipelined =====
      const _Float16* aH = hb + hbase + (size_t)((s & 1) * B_ + mrow) * H_ + kq * 256 + fkb * 8;
      f16x8 hf0, hf1, hf2, hf3, hf4, hf5, hf6, hf7;
      HLOAD(0, 0); HLOAD(1, 1); HLOAD(2, 2); HLOAD(3, 3);
      HLOAD(4, 4); HLOAD(5, 5); HLOAD(6, 6); HLOAD(7, 7);
      WAITV(4);
      HSTEP(0, 0); HSTEP(1, 1); HSTEP(2, 2); HSTEP(3, 3);
      WAITV(0);
      HSTEP(4, 4); HSTEP(5, 5); HSTEP(6, 6); HSTEP(7, 7);
    }

    // ===== partial-gate write: [kq][m][n], D layout col=lane&15, row=(lane>>4)*4+i =====
#pragma unroll
    for (int i = 0; i < 4; ++i) {
      const int m = mh * 16 + fkb * 4 + i;
      pg[kq][m][ 0 + frow] = acc0[i];
      pg[kq][m][16 + frow] = acc1[i];
      pg[kq][m][32 + frow] = acc2[i];
      pg[kq][m][48 + frow] = acc3[i];
    }
    __syncthreads();

    // ===== phase 4: gates / state update (thread = (batch tb, col thc)) =====
    float xi = pg[0][tb][ 0 + thc] + pg[1][tb][ 0 + thc] + pg[2][tb][ 0 + thc] + pg[3][tb][ 0 + thc] + b0;
    float xf = pg[0][tb][16 + thc] + pg[1][tb][16 + thc] + pg[2][tb][16 + thc] + pg[3][tb][16 + thc] + b1;
    float xg = pg[0][tb][32 + thc] + pg[1][tb][32 + thc] + pg[2][tb][32 + thc] + pg[3][tb][32 + thc] + b2;
    float xo = pg[0][tb][48 + thc] + pg[1][tb][48 + thc] + pg[2][tb][48 + thc] + pg[3][tb][48 + thc] + b3;
    float ig = fminf(fmaxf(0.2f * xi + 0.5f, 0.f), 1.f);
    float fg = fminf(fmaxf(0.2f * xf + 0.5f, 0.f), 1.f);
    float cg = fminf(fmaxf(xg, -1.f), 1.f);
    float og = fminf(fmaxf(0.2f * xo + 0.5f, 0.f), 1.f);
    c = fg * c + ig * cg;
    float hv = og * fminf(fmaxf(c, -1.f), 1.f);

    out[((size_t)tx * B_ + tb) * (2 * H_) + dir * H_ + tcol] = hv;   // plain cached store
    { // coherent h publish: write-through to MALL, buffer (s+1)&1
      const _Float16* hp = hb + hbase + (size_t)(((s + 1) & 1) * B_ + tb) * H_ + tcol;
      unsigned hbits = (unsigned)__builtin_bit_cast(unsigned short, (_Float16)hv);
      asm volatile("global_store_short %0, %1, off sc0 sc1" :: "v"(hp), "v"(hbits) : "memory");
    }
    if (s == T_ - 1) {
      const size_t HY = (size_t)T_ * B_ * 2 * H_;
      out[HY + ((size_t)dir * B_ + tb) * H_ + tcol] = hv;                           // hy
      out[HY + (size_t)2 * B_ * H_ + ((size_t)dir * B_ + tb) * H_ + tcol] = c;      // cy
    }

    // ===== phase 5: release + arrive =====
    asm volatile("s_waitcnt vmcnt(0)" ::: "memory");   // own h store ack'd at MALL
    __syncthreads();                                   // all 512 threads ack'd; pg reads done
    if (tid == 0)
      __hip_atomic_store(fl + slot, (unsigned)(s + 1), __ATOMIC_RELAXED, __HIP_MEMORY_SCOPE_AGENT);
    // next iteration's x-part overlaps flag propagation
  }
}

// ---------------------------------------------------------------- launcher
extern "C" void kernel_launch(void* const* d_in, const int* in_sizes, int n_in,
                              void* d_out, int out_size, void* d_ws, size_t ws_size,
                              hipStream_t stream) {
  const float* x      = (const float*)d_in[0];
  const float* w_ih_f = (const float*)d_in[1];
  const float* w_hh_f = (const float*)d_in[2];
  const float* b_ih_f = (const float*)d_in[3];
  const float* b_hh_f = (const float*)d_in[4];
  const float* w_ih_r = (const float*)d_in[5];
  const float* w_hh_r = (const float*)d_in[6];
  const float* b_ih_r = (const float*)d_in[7];
  const float* b_hh_r = (const float*)d_in[8];
  float* out = (float*)d_out;

  char* ws = (char*)d_ws;
  _Float16* xb    = (_Float16*)ws;                        // 16,384,000 B  (T*B*IN f16)
  _Float16* hb    = (_Float16*)(ws + 16384000);           //    262,144 B  (2 dir * 2 buf * B * H f16)
  unsigned* flags = (unsigned*)(ws + 16384000 + 262144);  //      1,024 B

  hipMemsetAsync(flags, 0, 1024, stream);
  cvt_x_kernel<<<4000, 256, 0, stream>>>(x, xb, 1024000);
  lstm_kernel<<<NWG, THR, 0, stream>>>(w_ih_f, w_hh_f, b_ih_f, b_hh_f,
                                       w_ih_r, w_hh_r, b_ih_r, b_hh_r,
                                       xb, hb, flags, out);
}